// Round 7
// baseline (1757.661 us; speedup 1.0000x reference)
//
#include <hip/hip_runtime.h>
#include <stdint.h>

// SuperRGCNLayer on MI355X — round 7 (identical to rounds 4-6; infra failures).
// out[d] = bias + sum_{r8} W[rel(dt(d),r8)] @ (sum_{e->d, grp r8} x[src_e])
// Edges counting-sorted by dst; one block owns 32 dsts -> zero output atomics.
// ws need: 262144 + 12*N + ~16 + 4*E bytes  (~7.9 MB for N=100K, E=1.6M)

#define TPB 256
#define DPB 32  // dsts per k_main block

// A8 row (ld,c) starts at (ld*8+c)*76 + ((ld&6)<<1).
//  - stride 76 floats (304 B ≡ 0 mod 16): float4-aligned rows.
//  - skew (ld&6)<<1 ∈ {0,4,8,12}: phase-B's 4 broadcast rows per wave
//    (ld even-set or odd-set; ld*608 ≡ 0 mod 32) land at bank offsets
//    {0,4,8,12} -> the wave's 4 distinct ds_read_b128 cover disjoint banks.
//  - overlap-free: gap = 12 + skew(next)-skew(cur) >= 0 (worst case 7->8: 0).
#define A8IDX(ld, c) (((ld) * 8 + (c)) * 76 + (((ld) & 6) << 1))

// ---- Wt[m][i][o] = sum_b w_comp[o%16][b] * weight[(m*4+o/16)*512 + b*64 + i]
__global__ void k_build_w(const float* __restrict__ weight,
                          const float* __restrict__ w_comp,
                          float* __restrict__ Wt) {
  const int idx = blockIdx.x * TPB + threadIdx.x;
  if (idx >= 16 * 64 * 64) return;
  const int m = idx >> 12, i = (idx >> 6) & 63, o = idx & 63;
  const float* wc = w_comp + ((o & 15) << 3);
  const float* wf = weight + (((m << 2) + (o >> 4)) << 9) + i;
  float s = 0.f;
#pragma unroll
  for (int b = 0; b < 8; ++b) s = fmaf(wc[b], wf[b << 6], s);
  Wt[idx] = s;
}

__global__ void k_zero(int* __restrict__ p, int n) {
  const int i = blockIdx.x * 1024 + threadIdx.x;
  if (i < n) p[i] = 0;
}

__global__ void k_hist(const int* __restrict__ edst, int* __restrict__ cntD, int E) {
  const int e = blockIdx.x * TPB + threadIdx.x;
  if (e < E) atomicAdd(&cntD[edst[e]], 1);
}

// single-block exclusive scan over N bins -> offsD[N+1], cursor
#define SCAN_T 1024
__global__ void k_scan(const int* __restrict__ cnt, int* __restrict__ offs,
                       int* __restrict__ cursor, int N) {
  __shared__ int ps[SCAN_T];
  const int tid = threadIdx.x;
  const int chunk = (N + SCAN_T - 1) / SCAN_T;
  const int b = tid * chunk, e = min(b + chunk, N);
  int s = 0;
  for (int i = b; i < e; ++i) s += cnt[i];
  ps[tid] = s;
  __syncthreads();
  for (int off = 1; off < SCAN_T; off <<= 1) {  // inclusive Hillis-Steele
    int v = 0;
    if (tid >= off) v = ps[tid - off];
    __syncthreads();
    ps[tid] += v;
    __syncthreads();
  }
  int run = (tid > 0) ? ps[tid - 1] : 0;
  for (int i = b; i < e; ++i) { offs[i] = run; cursor[i] = run; run += cnt[i]; }
  if (tid == SCAN_T - 1) offs[N] = run;
}

// scatter: packS[pos] = src | r8<<24, pos per-dst cursor
__global__ void k_scatter(const int* __restrict__ nt, const int* __restrict__ esrc,
                          const int* __restrict__ edst, const int* __restrict__ etyp,
                          int* __restrict__ cursor, uint32_t* __restrict__ packS, int E) {
  const int e = blockIdx.x * TPB + threadIdx.x;
  if (e < E) {
    const int s = esrc[e];
    const uint32_t r8 = (uint32_t)(nt[s] * 4 + etyp[e]);
    const int pos = atomicAdd(&cursor[edst[e]], 1);
    packS[pos] = (uint32_t)s | (r8 << 24);
  }
}

// ---- main fused kernel --------------------------------------------------
__global__ __launch_bounds__(TPB) void k_main(
    const float* __restrict__ x, const float* __restrict__ Wt,
    const int* __restrict__ offsD, const uint32_t* __restrict__ packS,
    const int* __restrict__ nt, const float* __restrict__ bias,
    float* __restrict__ out, int N) {
  __shared__ float A8[DPB * 8 * 76 + 16];  // skewed rows, see A8IDX
  __shared__ int offs[DPB + 1];
  __shared__ int ntl[DPB];
  const int tid = threadIdx.x;
  const int d0 = blockIdx.x * DPB;
  const int nd = min(DPB, N - d0);
  if (tid <= nd) offs[tid] = offsD[d0 + tid];
  if (tid < nd) ntl[tid] = nt[d0 + tid];
  __syncthreads();

  // ---- phase A: per-dst segment sums into A8 (wave-per-dst, no atomics)
  const int w = tid >> 6, lane = tid & 63;
  for (int ld = w; ld < DPB; ld += 4) {
    float racc[8] = {0.f, 0.f, 0.f, 0.f, 0.f, 0.f, 0.f, 0.f};
    if (ld < nd) {
      const int j0 = offs[ld], j1 = offs[ld + 1];
      for (int j = j0; j < j1; j += 8) {
        uint32_t pk[8];
        float xv[8];
#pragma unroll
        for (int u = 0; u < 8; ++u) {
          const int jj = min(j + u, j1 - 1);
          pk[u] = packS[jj];
        }
#pragma unroll
        for (int u = 0; u < 8; ++u)
          xv[u] = x[((size_t)(pk[u] & 0x00FFFFFFu) << 6) + lane];
#pragma unroll
        for (int u = 0; u < 8; ++u) {
          const float v = (j + u < j1) ? xv[u] : 0.f;
          switch (pk[u] >> 24) {  // wave-uniform branch (pk same across lanes)
            case 0: racc[0] += v; break;
            case 1: racc[1] += v; break;
            case 2: racc[2] += v; break;
            case 3: racc[3] += v; break;
            case 4: racc[4] += v; break;
            case 5: racc[5] += v; break;
            case 6: racc[6] += v; break;
            default: racc[7] += v; break;
          }
        }
      }
    }
#pragma unroll
    for (int c = 0; c < 8; ++c) A8[A8IDX(ld, c) + lane] = racc[c];
  }
  __syncthreads();

  // ---- phase B: Out[32][64] = bias + sum_r8 A8[:,r8,:] @ W[rel(dt,r8)]
  const int co = tid & 15, re = tid >> 4;
  const int ld0 = re * 2, ld1 = re * 2 + 1;
  float acc[2][4];
#pragma unroll
  for (int j = 0; j < 4; ++j) {
    const float bv = bias[(co << 2) + j];
    acc[0][j] = bv;
    acc[1][j] = bv;
  }
  const int t0 = (ld0 < nd) ? ntl[ld0] : 0;
  const int t1 = (ld1 < nd) ? ntl[ld1] : 0;
  const float4* Wt4 = (const float4*)Wt;
#pragma unroll 2
  for (int r8 = 0; r8 < 8; ++r8) {
    // rel = st*8 + dt*4 + et ; r8 = st*4 + et
    const int rel0 = ((r8 >> 2) << 3) + (t0 << 2) + (r8 & 3);
    const int rel1 = ((r8 >> 2) << 3) + (t1 << 2) + (r8 & 3);
    const float4* wp0 = Wt4 + (rel0 << 10) + co;  // Wt[rel][k][co*4] as float4
    const float4* wp1 = Wt4 + (rel1 << 10) + co;
    const float* a0 = &A8[A8IDX(ld0, r8)];
    const float* a1 = &A8[A8IDX(ld1, r8)];
    for (int k4 = 0; k4 < 64; k4 += 4) {
      const float4 av0 = *(const float4*)(a0 + k4);
      const float4 av1 = *(const float4*)(a1 + k4);
#pragma unroll
      for (int kk = 0; kk < 4; ++kk) {
        const float4 w0 = wp0[(k4 + kk) << 4];
        const float4 w1 = wp1[(k4 + kk) << 4];
        const float f0 = ((const float*)&av0)[kk];
        const float f1 = ((const float*)&av1)[kk];
        acc[0][0] = fmaf(f0, w0.x, acc[0][0]); acc[0][1] = fmaf(f0, w0.y, acc[0][1]);
        acc[0][2] = fmaf(f0, w0.z, acc[0][2]); acc[0][3] = fmaf(f0, w0.w, acc[0][3]);
        acc[1][0] = fmaf(f1, w1.x, acc[1][0]); acc[1][1] = fmaf(f1, w1.y, acc[1][1]);
        acc[1][2] = fmaf(f1, w1.z, acc[1][2]); acc[1][3] = fmaf(f1, w1.w, acc[1][3]);
      }
    }
  }

  // ---- phase C: plain stores, no atomics
  if (ld0 < nd) {
    float4 v = {acc[0][0], acc[0][1], acc[0][2], acc[0][3]};
    *(float4*)(out + ((size_t)(d0 + ld0) << 6) + (co << 2)) = v;
  }
  if (ld1 < nd) {
    float4 v = {acc[1][0], acc[1][1], acc[1][2], acc[1][3]};
    *(float4*)(out + ((size_t)(d0 + ld1) << 6) + (co << 2)) = v;
  }
}

// ---- launch ---------------------------------------------------------------
extern "C" void kernel_launch(void* const* d_in, const int* in_sizes, int n_in,
                              void* d_out, int out_size, void* d_ws, size_t ws_size,
                              hipStream_t stream) {
  const float* x      = (const float*)d_in[0];
  const int* nt       = (const int*)d_in[1];
  const int* esrc     = (const int*)d_in[2];
  const int* edst     = (const int*)d_in[3];
  const int* etyp     = (const int*)d_in[4];
  const float* weight = (const float*)d_in[5];
  const float* w_comp = (const float*)d_in[6];
  const float* bias   = (const float*)d_in[7];
  float* out = (float*)d_out;
  const int N = in_sizes[1];
  const int E = in_sizes[2];

  char* wsp = (char*)d_ws;
  size_t off = 0;
  float* Wt = (float*)(wsp + off); off += 262144;
  int* cntD = (int*)(wsp + off); off += (size_t)N * 4;
  int* offsD = (int*)(wsp + off); off += (size_t)(N + 1) * 4 + 12;  // keep 16B align
  int* cursor = (int*)(wsp + off); off += (size_t)N * 4;
  uint32_t* packS = (uint32_t*)(wsp + off); off += (size_t)E * 4;
  if (ws_size < off) return;

  const int ebl = (E + TPB - 1) / TPB;

  hipLaunchKernelGGL(k_zero, dim3((N + 1023) / 1024), dim3(1024), 0, stream, cntD, N);
  hipLaunchKernelGGL(k_build_w, dim3(256), dim3(TPB), 0, stream, weight, w_comp, Wt);
  hipLaunchKernelGGL(k_hist, dim3(ebl), dim3(TPB), 0, stream, edst, cntD, E);
  hipLaunchKernelGGL(k_scan, dim3(1), dim3(SCAN_T), 0, stream, cntD, offsD, cursor, N);
  hipLaunchKernelGGL(k_scatter, dim3(ebl), dim3(TPB), 0, stream, nt, esrc, edst, etyp,
                     cursor, packS, E);
  hipLaunchKernelGGL(k_main, dim3((N + DPB - 1) / DPB), dim3(TPB), 0, stream,
                     x, Wt, offsD, packS, nt, bias, out, N);
}